// Round 2
// baseline (2069.253 us; speedup 1.0000x reference)
//
#include <hip/hip_runtime.h>
#include <float.h>

#define D_DIM 512
#define BM 64
#define BK 128
#define BD 32
#define ZS_STRIDE (BM + 4)   // 68 floats: 16B-aligned rows
#define CS_STRIDE (BK + 4)   // 132 floats

// ---------------- kernel 1: codebook squared norms (f32+f64) + zero freq ----
__global__ __launch_bounds__(256) void csq_kernel(const float* __restrict__ cb,
                                                  float* __restrict__ csq32,
                                                  double* __restrict__ csq64,
                                                  float* __restrict__ freq,
                                                  int K) {
    int tid = threadIdx.x;
    int gt = blockIdx.x * 256 + tid;
    if (gt < K) freq[gt] = 0.0f;

    int wave = tid >> 6, lane = tid & 63;
    int k = blockIdx.x * 4 + wave;
    if (k >= K) return;
    const float* row = cb + (size_t)k * D_DIM;
    float4 v0 = *(const float4*)(row + lane * 4);
    float4 v1 = *(const float4*)(row + 256 + lane * 4);
    double s = (double)v0.x * v0.x + (double)v0.y * v0.y +
               (double)v0.z * v0.z + (double)v0.w * v0.w +
               (double)v1.x * v1.x + (double)v1.y * v1.y +
               (double)v1.z * v1.z + (double)v1.w * v1.w;
    #pragma unroll
    for (int off = 32; off > 0; off >>= 1) s += __shfl_down(s, off);
    if (lane == 0) { csq64[k] = s; csq32[k] = (float)s; }
}

// ---------------- top-4 insert (ascending) ---------------------------------
__device__ __forceinline__ void top4_insert(float (&v)[4], int (&ki)[4], float s, int k) {
    if (s < v[3]) {
        v[3] = s; ki[3] = k;
        if (v[3] < v[2]) {
            float t = v[3]; v[3] = v[2]; v[2] = t; int u = ki[3]; ki[3] = ki[2]; ki[2] = u;
            if (v[2] < v[1]) {
                t = v[2]; v[2] = v[1]; v[1] = t; u = ki[2]; ki[2] = ki[1]; ki[1] = u;
                if (v[1] < v[0]) {
                    t = v[1]; v[1] = v[0]; v[0] = t; u = ki[1]; ki[1] = ki[0]; ki[0] = u;
                }
            }
        }
    }
}

// ---------------- pass 1: f32 GEMM + per-row top-4 candidates --------------
__global__ __launch_bounds__(256) void pass1_kernel(const float* __restrict__ z,
                                                    const float* __restrict__ cb,
                                                    const float* __restrict__ csq32,
                                                    float* __restrict__ cand_v,
                                                    int* __restrict__ cand_i,
                                                    int K) {
    __shared__ float zs[BD][ZS_STRIDE];
    __shared__ float cs[BD][CS_STRIDE];
    __shared__ float mv[BM][64];   // 64 candidate slots per row (16 col-groups x top-4)
    __shared__ int   mi[BM][64];

    const int tid = threadIdx.x;
    const int rg = tid & 15;   // row group: rows rg*4 .. rg*4+3
    const int cg = tid >> 4;   // col group 0..15: cols cg*8 .. cg*8+7
    const int row0 = blockIdx.x * BM;

    float tv[4][4]; int tk[4][4];
    #pragma unroll
    for (int r = 0; r < 4; ++r)
        #pragma unroll
        for (int m = 0; m < 4; ++m) { tv[r][m] = FLT_MAX; tk[r][m] = 0x7fffffff; }

    for (int kt = 0; kt < K; kt += BK) {
        float acc[4][8];
        #pragma unroll
        for (int r = 0; r < 4; ++r)
            #pragma unroll
            for (int c = 0; c < 8; ++c) acc[r][c] = 0.0f;

        for (int dt = 0; dt < D_DIM; dt += BD) {
            __syncthreads();
            // stage z tile: 64 rows x 32 d, transposed into zs[d][row]
            #pragma unroll
            for (int i = 0; i < 2; ++i) {
                int lin = tid + i * 256;          // float4 id 0..511
                int zr = lin >> 3;                // 0..63
                int dg = lin & 7;                 // 0..7
                float4 v = *(const float4*)(z + (size_t)(row0 + zr) * D_DIM + dt + dg * 4);
                zs[dg * 4 + 0][zr] = v.x; zs[dg * 4 + 1][zr] = v.y;
                zs[dg * 4 + 2][zr] = v.z; zs[dg * 4 + 3][zr] = v.w;
            }
            // stage c tile: 128 rows x 32 d, transposed into cs[d][code]
            #pragma unroll
            for (int i = 0; i < 4; ++i) {
                int lin = tid + i * 256;          // float4 id 0..1023
                int cr = lin >> 3;                // 0..127
                int dg = lin & 7;
                float4 v = *(const float4*)(cb + (size_t)(kt + cr) * D_DIM + dt + dg * 4);
                cs[dg * 4 + 0][cr] = v.x; cs[dg * 4 + 1][cr] = v.y;
                cs[dg * 4 + 2][cr] = v.z; cs[dg * 4 + 3][cr] = v.w;
            }
            __syncthreads();

            #pragma unroll
            for (int d = 0; d < BD; ++d) {
                float4 a  = *(const float4*)&zs[d][rg * 4];
                float4 b0 = *(const float4*)&cs[d][cg * 8];
                float4 b1 = *(const float4*)&cs[d][cg * 8 + 4];
                float av[4] = {a.x, a.y, a.z, a.w};
                float bv[8] = {b0.x, b0.y, b0.z, b0.w, b1.x, b1.y, b1.z, b1.w};
                #pragma unroll
                for (int r = 0; r < 4; ++r)
                    #pragma unroll
                    for (int c = 0; c < 8; ++c)
                        acc[r][c] = fmaf(av[r], bv[c], acc[r][c]);
            }
        }
        // epilogue: scores + top-4 update (k ascending within thread)
        #pragma unroll
        for (int c = 0; c < 8; ++c) {
            int k = kt + cg * 8 + c;
            float cq = csq32[k];
            #pragma unroll
            for (int r = 0; r < 4; ++r) {
                float s = fmaf(-2.0f, acc[r][c], cq);
                top4_insert(tv[r], tk[r], s, k);
            }
        }
    }

    // merge: each row has 16 col-group threads x 4 candidates = 64 slots
    __syncthreads();
    #pragma unroll
    for (int r = 0; r < 4; ++r)
        #pragma unroll
        for (int m = 0; m < 4; ++m) {
            mv[rg * 4 + r][cg * 4 + m] = tv[r][m];
            mi[rg * 4 + r][cg * 4 + m] = tk[r][m];
        }
    __syncthreads();
    if (tid < BM) {
        int row = tid;
        float bv[4] = {FLT_MAX, FLT_MAX, FLT_MAX, FLT_MAX};
        int   bk[4] = {0x7fffffff, 0x7fffffff, 0x7fffffff, 0x7fffffff};
        for (int j = 0; j < 64; ++j)
            top4_insert(bv, bk, mv[row][j], mi[row][j]);
        #pragma unroll
        for (int m = 0; m < 4; ++m) {
            cand_v[(size_t)(row0 + row) * 4 + m] = bv[m];
            cand_i[(size_t)(row0 + row) * 4 + m] = bk[m];
        }
    }
}

// ---------------- pass 2: f64 rescoring of candidates + outputs ------------
__global__ __launch_bounds__(256) void pass2_kernel(const float* __restrict__ z,
                                                    const float* __restrict__ cb,
                                                    const double* __restrict__ csq64,
                                                    const float* __restrict__ cand_v,
                                                    const int* __restrict__ cand_i,
                                                    float* __restrict__ zq,
                                                    float* __restrict__ oidx,
                                                    float* __restrict__ freq,
                                                    int N, int K) {
    int lane = threadIdx.x & 63;
    int row = blockIdx.x * 4 + (threadIdx.x >> 6);
    if (row >= N) return;

    const float* zrow = z + (size_t)row * D_DIM;
    float4 z0 = *(const float4*)(zrow + lane * 4);
    float4 z1 = *(const float4*)(zrow + 256 + lane * 4);

    float cv0 = cand_v[(size_t)row * 4 + 0];
    float cv3 = cand_v[(size_t)row * 4 + 3];

    int ci[4];
    bool ok = (cv3 - cv0 >= 0.1f);
    #pragma unroll
    for (int m = 0; m < 4; ++m) {
        ci[m] = cand_i[(size_t)row * 4 + m];
        if (ci[m] < 0 || ci[m] >= K) ok = false;   // defensive: force full scan
    }

    double best_s = DBL_MAX;
    int best_k = 0;

    if (ok) {
        // top-4 provably contains the exact argmin (margin >= 2*e_f32)
        #pragma unroll
        for (int m = 0; m < 4; ++m) {
            int k = ci[m];
            const float* crow = cb + (size_t)k * D_DIM;
            float4 c0 = *(const float4*)(crow + lane * 4);
            float4 c1 = *(const float4*)(crow + 256 + lane * 4);
            double acc = (double)z0.x * c0.x + (double)z0.y * c0.y +
                         (double)z0.z * c0.z + (double)z0.w * c0.w +
                         (double)z1.x * c1.x + (double)z1.y * c1.y +
                         (double)z1.z * c1.z + (double)z1.w * c1.w;
            #pragma unroll
            for (int off = 32; off > 0; off >>= 1) acc += __shfl_down(acc, off);
            if (lane == 0) {
                double s = csq64[k] - 2.0 * acc;
                if (s < best_s || (s == best_s && k < best_k)) { best_s = s; best_k = k; }
            }
        }
    } else {
        // rare near-tie cluster (or defensive fallback): exact full scan
        for (int k = 0; k < K; ++k) {
            const float* crow = cb + (size_t)k * D_DIM;
            float4 c0 = *(const float4*)(crow + lane * 4);
            float4 c1 = *(const float4*)(crow + 256 + lane * 4);
            double acc = (double)z0.x * c0.x + (double)z0.y * c0.y +
                         (double)z0.z * c0.z + (double)z0.w * c0.w +
                         (double)z1.x * c1.x + (double)z1.y * c1.y +
                         (double)z1.z * c1.z + (double)z1.w * c1.w;
            #pragma unroll
            for (int off = 32; off > 0; off >>= 1) acc += __shfl_down(acc, off);
            if (lane == 0) {
                double s = csq64[k] - 2.0 * acc;
                if (s < best_s) { best_s = s; best_k = k; }
            }
        }
    }

    best_k = __shfl(best_k, 0);
    if (lane == 0) {
        oidx[row] = (float)best_k;
        atomicAdd(&freq[best_k], 1.0f);
    }
    // gather z_q = codebook[best_k] (exact -> bitwise match)
    const float* crow = cb + (size_t)best_k * D_DIM;
    *(float4*)(zq + (size_t)row * D_DIM + lane * 4) = *(const float4*)(crow + lane * 4);
    *(float4*)(zq + (size_t)row * D_DIM + 256 + lane * 4) = *(const float4*)(crow + 256 + lane * 4);
}

// ---------------- launcher --------------------------------------------------
extern "C" void kernel_launch(void* const* d_in, const int* in_sizes, int n_in,
                              void* d_out, int out_size, void* d_ws, size_t ws_size,
                              hipStream_t stream) {
    const float* z  = (const float*)d_in[0];
    const float* cb = (const float*)d_in[1];
    const int N = in_sizes[0] / D_DIM;   // 32768
    const int K = in_sizes[1] / D_DIM;   // 4096

    float* zq   = (float*)d_out;                 // [N, D]
    float* oidx = zq + (size_t)N * D_DIM;        // [N] indices as float
    float* freq = oidx + N;                      // [K]

    char* ws = (char*)d_ws;
    size_t o = 0;
    float*  csq32 = (float*)(ws + o);  o += (size_t)K * sizeof(float);
    o = (o + 255) & ~(size_t)255;
    double* csq64 = (double*)(ws + o); o += (size_t)K * sizeof(double);
    o = (o + 255) & ~(size_t)255;
    float*  cand_v = (float*)(ws + o); o += (size_t)N * 4 * sizeof(float);
    int*    cand_i = (int*)(ws + o);

    hipLaunchKernelGGL(csq_kernel, dim3((K + 3) / 4), dim3(256), 0, stream,
                       cb, csq32, csq64, freq, K);
    hipLaunchKernelGGL(pass1_kernel, dim3(N / BM), dim3(256), 0, stream,
                       z, cb, csq32, cand_v, cand_i, K);
    hipLaunchKernelGGL(pass2_kernel, dim3(N / 4), dim3(256), 0, stream,
                       z, cb, csq64, cand_v, cand_i, zq, oidx, freq, N, K);
}